// Round 1
// baseline (460.596 us; speedup 1.0000x reference)
//
#include <hip/hip_runtime.h>
#include <hip/hip_bf16.h>
#include <stdint.h>

// Problem dims: B=16, C=512, H=W=32, NH=8, HC=64, HW=1024, 3C=1536
#define Bn  16
#define Cch 512
#define C3  1536
#define HWp 1024

typedef __attribute__((ext_vector_type(8))) short bf16x8;   // 8 bf16 = 4 VGPRs (MFMA A/B frag)
typedef __attribute__((ext_vector_type(4))) float f32x4;    // MFMA C/D frag

#define DEV static __device__ __forceinline__

DEV float bflo(unsigned u) { return __builtin_bit_cast(float, u << 16); }
DEV float bfhi(unsigned u) { return __builtin_bit_cast(float, u & 0xffff0000u); }
DEV unsigned short f2bf(float f) {
  __hip_bfloat16 h = __float2bfloat16(f);
  return __builtin_bit_cast(unsigned short, h);
}

// ---------------- 1. weight prep: fp32 -> bf16 ----------------
// Wpw[2][1536][512] (row-major o,c) ; projT[512][1024] = proj^T (c rows, d contiguous)
__global__ __launch_bounds__(256) void k_prep(
    const float* __restrict__ img_pw_w, const float* __restrict__ wm_pw_w,
    const float* __restrict__ proj,
    __hip_bfloat16* __restrict__ Wpw, __hip_bfloat16* __restrict__ projT)
{
  int i = blockIdx.x * 256 + threadIdx.x;
  const int NW = C3 * Cch;  // 786432
  if (i < NW)          Wpw[i] = __float2bfloat16(img_pw_w[i]);
  else if (i < 2 * NW) Wpw[i] = __float2bfloat16(wm_pw_w[i - NW]);
  else {
    int j = i - 2 * NW;                 // 0..524287
    int c = j >> 10, d = j & 1023;
    projT[(size_t)c * 1024 + d] = __float2bfloat16(proj[(size_t)d * 512 + c]);
  }
}

// ---------------- 2. LayerNorm partial sums ----------------
// grid 2048 = t(2) * b(16) * chunk(64); each block reduces 8192 elems
__global__ __launch_bounds__(256) void k_ln_partial(
    const float* __restrict__ image, const float* __restrict__ watermark,
    float* __restrict__ part)
{
  int blk = blockIdx.x;
  int chunk = blk & 63, b = (blk >> 6) & 15, t = blk >> 10;
  const float* x = (t ? watermark : image) + (size_t)b * Cch * HWp + chunk * 8192;
  const float4* xv = (const float4*)x;
  float s = 0.f, ss = 0.f;
#pragma unroll
  for (int i = 0; i < 8; i++) {
    float4 v = xv[threadIdx.x + i * 256];
    s  += v.x + v.y + v.z + v.w;
    ss += v.x * v.x + v.y * v.y + v.z * v.z + v.w * v.w;
  }
#pragma unroll
  for (int off = 32; off; off >>= 1) { s += __shfl_down(s, off); ss += __shfl_down(ss, off); }
  __shared__ float ls[4], lss[4];
  int wv = threadIdx.x >> 6;
  if ((threadIdx.x & 63) == 0) { ls[wv] = s; lss[wv] = ss; }
  __syncthreads();
  if (threadIdx.x == 0) {
    part[blk * 2]     = ls[0] + ls[1] + ls[2] + ls[3];
    part[blk * 2 + 1] = lss[0] + lss[1] + lss[2] + lss[3];
  }
}

// ---------------- 3. finalize mu / rstd (32 pairs) ----------------
__global__ void k_ln_final(const float* __restrict__ part, float* __restrict__ stats)
{
  int i = threadIdx.x;
  if (i < 32) {
    float S = 0.f, SS = 0.f;
    for (int c2 = 0; c2 < 64; c2++) { S += part[(i * 64 + c2) * 2]; SS += part[(i * 64 + c2) * 2 + 1]; }
    const float inv = 1.f / (float)(Cch * HWp);
    float mu  = S * inv;
    float var = SS * inv - mu * mu;
    stats[i]      = mu;
    stats[32 + i] = rsqrtf(var + 1e-5f);
  }
}

// ---------------- 4. normalize + affine + transpose -> xnT[t][b][p][c] bf16 ----------------
// 32x32 LDS tile transpose; grid 16384 = t*8192 + b*512 + pt*16 + ct
__global__ __launch_bounds__(256) void k_norm_t(
    const float* __restrict__ image, const float* __restrict__ watermark,
    const float* __restrict__ img_w, const float* __restrict__ img_b,
    const float* __restrict__ wm_w,  const float* __restrict__ wm_b,
    const float* __restrict__ stats, __hip_bfloat16* __restrict__ xnT)
{
  int blk = blockIdx.x;
  int ct = blk & 15, pt = (blk >> 4) & 31, b = (blk >> 9) & 15, t = blk >> 13;
  const float* x   = (t ? watermark : image) + (size_t)b * Cch * HWp;
  const float* wgt = t ? wm_w : img_w;
  const float* bia = t ? wm_b : img_b;
  float mu = stats[t * 16 + b], rstd = stats[32 + t * 16 + b];
  __shared__ float tile[32][33];
  int pl = threadIdx.x & 31, cl0 = threadIdx.x >> 5;
  int p = pt * 32 + pl;
#pragma unroll
  for (int k = 0; k < 4; k++) {
    int cl = cl0 + k * 8;
    int idx = (ct * 32 + cl) * HWp + p;
    tile[cl][pl] = (x[idx] - mu) * rstd * wgt[idx] + bia[idx];
  }
  __syncthreads();
  __hip_bfloat16* dst = xnT + ((size_t)(t * 16 + b)) * HWp * Cch;
#pragma unroll
  for (int k = 0; k < 4; k++) {
    int prow = cl0 + k * 8;
    dst[(size_t)(pt * 32 + prow) * Cch + ct * 32 + pl] = __float2bfloat16(tile[pl][prow]);
  }
}

// ---------------- 5. bf16 BT-GEMM core: C[m][n] = sum_k A[m][k]*Bt[n][k] ----------------
// 128x128 block tile, 4 waves (64x64 each, 4x4 of 16x16x32 MFMA), BK=32.
// LDS rows padded to 40 bf16 (80 B) -> ~2-way (free) bank aliasing on ds_read_b128.
template<int Kdim, int Ncols, bool OBF, bool HB>
DEV void gemm_core(const __hip_bfloat16* __restrict__ A,
                   const __hip_bfloat16* __restrict__ Bt,
                   const float* __restrict__ bias, void* __restrict__ Cout)
{
  __shared__ __hip_bfloat16 As[128 * 40];
  __shared__ __hip_bfloat16 Bs[128 * 40];
  const int tid = threadIdx.x, lane = tid & 63, wv = tid >> 6;
  const int lr = lane & 15, lq = lane >> 4;
  const int wm = (wv >> 1) * 64, wn = (wv & 1) * 64;
  const int m0 = blockIdx.y * 128, n0 = blockIdx.x * 128;
  f32x4 acc[4][4] = {};
  const int row_s = tid >> 2, seg_s = (tid & 3) * 8;
  for (int k0 = 0; k0 < Kdim; k0 += 32) {
#pragma unroll
    for (int s = 0; s < 2; s++) {
      int row = row_s + s * 64;
      *(uint4*)&As[row * 40 + seg_s] = *(const uint4*)&A [(size_t)(m0 + row) * Kdim + k0 + seg_s];
      *(uint4*)&Bs[row * 40 + seg_s] = *(const uint4*)&Bt[(size_t)(n0 + row) * Kdim + k0 + seg_s];
    }
    __syncthreads();
    bf16x8 af[4], bfr[4];
#pragma unroll
    for (int mi = 0; mi < 4; mi++) af[mi]  = *(const bf16x8*)&As[(wm + mi * 16 + lr) * 40 + lq * 8];
#pragma unroll
    for (int ni = 0; ni < 4; ni++) bfr[ni] = *(const bf16x8*)&Bs[(wn + ni * 16 + lr) * 40 + lq * 8];
#pragma unroll
    for (int mi = 0; mi < 4; mi++)
#pragma unroll
      for (int ni = 0; ni < 4; ni++)
        acc[mi][ni] = __builtin_amdgcn_mfma_f32_16x16x32_bf16(af[mi], bfr[ni], acc[mi][ni], 0, 0, 0);
    __syncthreads();
  }
  // epilogue: D[row=4*(l/16)+r (+tiles)][col=l%16 (+tiles)]
#pragma unroll
  for (int mi = 0; mi < 4; mi++) {
    int mrow = m0 + wm + mi * 16 + lq * 4;
#pragma unroll
    for (int ni = 0; ni < 4; ni++) {
      int ncol = n0 + wn + ni * 16 + lr;
#pragma unroll
      for (int r = 0; r < 4; r++) {
        float y = acc[mi][ni][r];
        int row = mrow + r;
        if (HB) y += bias[row];
        if (OBF) ((__hip_bfloat16*)Cout)[(size_t)row * Ncols + ncol] = __float2bfloat16(y);
        else     ((float*)Cout)[(size_t)row * Ncols + ncol] = y;
      }
    }
  }
}

// pointwise: per (t,b): Y[1536][1024] = Wpw[t][1536][512] x xnT[t][b][1024][512]^T + bias
__global__ __launch_bounds__(256) void k_pw_gemm(
    const __hip_bfloat16* __restrict__ Wpw, const __hip_bfloat16* __restrict__ xnT,
    const float* __restrict__ img_pw_b, const float* __restrict__ wm_pw_b,
    __hip_bfloat16* __restrict__ Y)
{
  int bz = blockIdx.z, t = bz >> 4;
  gemm_core<512, 1024, true, true>(
      Wpw + (size_t)t * C3 * Cch,
      xnT + (size_t)bz * HWp * Cch,
      t ? wm_pw_b : img_pw_b,
      Y + (size_t)bz * C3 * HWp);
}

// final projection: per b: out[512][1024] = projT[512][1024] x attnT[b][1024][1024]^T (fp32 out)
__global__ __launch_bounds__(256) void k_proj_gemm(
    const __hip_bfloat16* __restrict__ projT, const __hip_bfloat16* __restrict__ attnT,
    float* __restrict__ out)
{
  int b = blockIdx.z;
  gemm_core<1024, 1024, false, false>(
      projT, attnT + (size_t)b * HWp * 1024, nullptr, out + (size_t)b * Cch * HWp);
}

// ---------------- 6. depthwise 3x3 grouped conv (groups of 3 in -> 3 out) ----------------
// thread = (tb, o, h, w-chunk of 8); QKV[t][b][o][p] bf16
__global__ __launch_bounds__(256) void k_dw(
    const __hip_bfloat16* __restrict__ Y,
    const float* __restrict__ img_dw_w, const float* __restrict__ img_dw_b,
    const float* __restrict__ wm_dw_w,  const float* __restrict__ wm_dw_b,
    __hip_bfloat16* __restrict__ QKV)
{
  int idx = blockIdx.x * 256 + threadIdx.x;
  int w0 = (idx & 3) * 8;
  int h  = (idx >> 2) & 31;
  int o  = (idx >> 7) % C3;       // wave-uniform
  int tb = idx / (C3 * 128);
  int t  = tb >> 4;
  const float* dww = (t ? wm_dw_w : img_dw_w) + o * 27;
  float bv = (t ? wm_dw_b : img_dw_b)[o];
  int g = o / 3;
  const __hip_bfloat16* base = Y + ((size_t)tb * C3 + g * 3) * HWp;
  float acc[8];
#pragma unroll
  for (int w = 0; w < 8; w++) acc[w] = bv;
#pragma unroll
  for (int i = 0; i < 3; i++) {
#pragma unroll
    for (int kh = 0; kh < 3; kh++) {
      int hh = h + kh - 1;
      if (hh < 0 || hh > 31) continue;
      // 12 halfs covering w0-2 .. w0+9 (dword aligned; OOB lanes masked below)
      const unsigned* up = (const unsigned*)(base + i * HWp + hh * 32 + (w0 - 2));
      float v[12];
#pragma unroll
      for (int d2 = 0; d2 < 6; d2++) { unsigned u = up[d2]; v[d2*2] = bflo(u); v[d2*2+1] = bfhi(u); }
#pragma unroll
      for (int pth = 0; pth < 12; pth++)
        if ((unsigned)(w0 - 2 + pth) >= 32u) v[pth] = 0.f;
      float wk0 = dww[i*9 + kh*3 + 0], wk1 = dww[i*9 + kh*3 + 1], wk2 = dww[i*9 + kh*3 + 2];
#pragma unroll
      for (int w = 0; w < 8; w++)
        acc[w] += v[w + 1] * wk0 + v[w + 2] * wk1 + v[w + 3] * wk2;
    }
  }
  union { unsigned short us[8]; uint4 v4; } pk;
#pragma unroll
  for (int w = 0; w < 8; w++) pk.us[w] = f2bf(acc[w]);
  *(uint4*)(QKV + ((size_t)tb * C3 + o) * HWp + h * 32 + w0) = pk.v4;
}

// ---------------- 7. attention scores + softmax over q ----------------
// S[k][q] = sum_p Kc[k][p] * Q_m[q][p]; softmax over q per k-row; ATg[bn][m][q][k] bf16
__global__ __launch_bounds__(256) void k_attn_scores(
    const __hip_bfloat16* __restrict__ QKV, __hip_bfloat16* __restrict__ ATg)
{
  int bn = blockIdx.x, b = bn >> 3, nh = bn & 7;
  int tid = threadIdx.x, lane = tid & 63, wv = tid >> 6;
  int lr = lane & 15, lq = lane >> 4;
  const __hip_bfloat16* kbase[2];
#pragma unroll
  for (int kt = 0; kt < 2; kt++) {
    int krow = wv * 32 + kt * 16 + lr;          // 0..127 ; <64 -> Ki, >=64 -> Kw
    int tk = krow >> 6, hc = krow & 63;
    kbase[kt] = QKV + (((size_t)(tk * 16 + b)) * C3 + 512 + nh * 64 + hc) * HWp + lq * 8;
  }
  const __hip_bfloat16* qbase[2][4];
#pragma unroll
  for (int m = 0; m < 2; m++)
#pragma unroll
    for (int qt = 0; qt < 4; qt++)
      qbase[m][qt] = QKV + (((size_t)(m * 16 + b)) * C3 + nh * 64 + qt * 16 + lr) * HWp + lq * 8;

  f32x4 acc[2][2][4] = {};
  for (int p0 = 0; p0 < HWp; p0 += 32) {
    bf16x8 af[2];
#pragma unroll
    for (int kt = 0; kt < 2; kt++) af[kt] = *(const bf16x8*)(kbase[kt] + p0);
#pragma unroll
    for (int m = 0; m < 2; m++)
#pragma unroll
      for (int qt = 0; qt < 4; qt++) {
        bf16x8 bq = *(const bf16x8*)(qbase[m][qt] + p0);
#pragma unroll
        for (int kt = 0; kt < 2; kt++)
          acc[m][kt][qt] = __builtin_amdgcn_mfma_f32_16x16x32_bf16(af[kt], bq, acc[m][kt][qt], 0, 0, 0);
      }
  }
  // S^T in LDS: [m][q][k] so softmax (over q) reads are conflict-free column walks
  __shared__ float SbufT[2][64][128];
#pragma unroll
  for (int m = 0; m < 2; m++)
#pragma unroll
    for (int kt = 0; kt < 2; kt++)
#pragma unroll
      for (int qt = 0; qt < 4; qt++)
#pragma unroll
        for (int r = 0; r < 4; r++)
          SbufT[m][qt * 16 + lr][wv * 32 + kt * 16 + lq * 4 + r] = acc[m][kt][qt][r];
  __syncthreads();
  int m = tid >> 7, k = tid & 127;   // 256 threads = 2m x 128k
  float vals[64], mx = -1e30f;
#pragma unroll
  for (int q = 0; q < 64; q++) { vals[q] = SbufT[m][q][k]; mx = fmaxf(mx, vals[q]); }
  float ssum = 0.f;
#pragma unroll
  for (int q = 0; q < 64; q++) { vals[q] = __expf(vals[q] - mx); ssum += vals[q]; }
  float inv = 1.f / ssum;
  __hip_bfloat16* outp = ATg + ((size_t)(bn * 2 + m)) * 64 * 128 + k;
#pragma unroll
  for (int q = 0; q < 64; q++) outp[(size_t)q * 128] = __float2bfloat16(vals[q] * inv);
}

// ---------------- 8. attention output: O[q][p] = sum_k AT[q][k] V[k][p] ----------------
// writes attnT[b][p][d] bf16 (d = nh*128 + m*64 + q), d-contiguous for the proj BT-GEMM
__global__ __launch_bounds__(256) void k_attn_out(
    const __hip_bfloat16* __restrict__ QKV, const __hip_bfloat16* __restrict__ ATg,
    __hip_bfloat16* __restrict__ attnT)
{
  int blk = blockIdx.x, pc = blk & 3, bn = blk >> 2, b = bn >> 3, nh = bn & 7;
  int tid = threadIdx.x, lane = tid & 63, wv = tid >> 6;
  int lr = lane & 15, lq = lane >> 4;
  __shared__ __hip_bfloat16 ATs[64][136];   // +8 pad: breaks 256B-stride conflicts
  __shared__ __hip_bfloat16 VTs[64][136];
  for (int m = 0; m < 2; m++) {
    __syncthreads();                        // prev compute done before ATs overwrite
    {
      const __hip_bfloat16* src = ATg + ((size_t)(bn * 2 + m)) * 64 * 128;
#pragma unroll
      for (int s = 0; s < 4; s++) {
        int id = tid + s * 256, row = id >> 4, seg = (id & 15) * 8;
        *(uint4*)&ATs[row][seg] = *(const uint4*)&src[row * 128 + seg];
      }
    }
    for (int ps = 0; ps < 4; ps++) {
      int p0 = pc * 256 + ps * 64;
      __syncthreads();                      // prev compute done before VTs overwrite (+ATs visible)
#pragma unroll
      for (int s = 0; s < 4; s++) {         // stage VTs[p][k] = V[k][p0+p]
        int id = tid + s * 256;
        int k = id >> 3, seg = (id & 7) * 8;
        int tk = k >> 6, hc = k & 63;
        const __hip_bfloat16* vp =
            QKV + (((size_t)(tk * 16 + b)) * C3 + 1024 + nh * 64 + hc) * HWp + p0 + seg;
        uint4 pkv = *(const uint4*)vp;
        unsigned short* pv = (unsigned short*)&pkv;
#pragma unroll
        for (int e = 0; e < 8; e++) *(unsigned short*)&VTs[seg + e][k] = pv[e];
      }
      __syncthreads();
      f32x4 oacc[4] = {};                   // per q-tile; this wave owns p-tile wv
#pragma unroll
      for (int ks = 0; ks < 4; ks++) {
        bf16x8 bv = *(const bf16x8*)&VTs[wv * 16 + lr][ks * 32 + lq * 8];
#pragma unroll
        for (int qt = 0; qt < 4; qt++) {
          bf16x8 av = *(const bf16x8*)&ATs[qt * 16 + lr][ks * 32 + lq * 8];
          oacc[qt] = __builtin_amdgcn_mfma_f32_16x16x32_bf16(av, bv, oacc[qt], 0, 0, 0);
        }
      }
#pragma unroll
      for (int qt = 0; qt < 4; qt++) {
        int q = qt * 16 + lq * 4;
        int d = nh * 128 + m * 64 + q;
        int p = p0 + wv * 16 + lr;
        union { unsigned short us[4]; uint2 v2; } pk;
#pragma unroll
        for (int r = 0; r < 4; r++) pk.us[r] = f2bf(oacc[qt][r]);
        *(uint2*)&attnT[((size_t)b * HWp + p) * 1024 + d] = pk.v2;
      }
    }
  }
}

extern "C" void kernel_launch(void* const* d_in, const int* in_sizes, int n_in,
                              void* d_out, int out_size, void* d_ws, size_t ws_size,
                              hipStream_t stream)
{
  (void)in_sizes; (void)n_in; (void)out_size; (void)ws_size;
  const float* image     = (const float*)d_in[0];
  const float* watermark = (const float*)d_in[1];
  const float* img_ln_w  = (const float*)d_in[2];
  const float* img_ln_b  = (const float*)d_in[3];
  const float* wm_ln_w   = (const float*)d_in[4];
  const float* wm_ln_b   = (const float*)d_in[5];
  const float* img_pw_w  = (const float*)d_in[6];
  const float* img_pw_b  = (const float*)d_in[7];
  const float* img_dw_w  = (const float*)d_in[8];
  const float* img_dw_b  = (const float*)d_in[9];
  const float* wm_pw_w   = (const float*)d_in[10];
  const float* wm_pw_b   = (const float*)d_in[11];
  const float* wm_dw_w   = (const float*)d_in[12];
  const float* wm_dw_b   = (const float*)d_in[13];
  const float* proj      = (const float*)d_in[14];

  char* ws = (char*)d_ws;
  // workspace map (high-water ~232 MiB); aliases are lifetime-disjoint:
  //   attnT aliases xnT (xnT dead after k_pw_gemm); ATg aliases Y (Y dead after k_dw)
  __hip_bfloat16* Wpw    = (__hip_bfloat16*)(ws + 0);            // 3.0 MiB
  __hip_bfloat16* projT  = (__hip_bfloat16*)(ws + 3145728);      // 1.0 MiB
  float*          lnpart = (float*)(ws + 4194304);               // 16 KiB
  float*          stats  = (float*)(ws + 4210688);               // 256 B
  __hip_bfloat16* xnT    = (__hip_bfloat16*)(ws + 5242880);      // 32 MiB
  __hip_bfloat16* attnT  = xnT;                                  // alias
  __hip_bfloat16* Y      = (__hip_bfloat16*)(ws + 41943040);     // 96 MiB
  __hip_bfloat16* ATg    = Y;                                    // alias (4 MiB)
  __hip_bfloat16* QKV    = (__hip_bfloat16*)(ws + 142606336);    // 96 MiB

  k_prep<<<8192, 256, 0, stream>>>(img_pw_w, wm_pw_w, proj, Wpw, projT);
  k_ln_partial<<<2048, 256, 0, stream>>>(image, watermark, lnpart);
  k_ln_final<<<1, 64, 0, stream>>>(lnpart, stats);
  k_norm_t<<<16384, 256, 0, stream>>>(image, watermark, img_ln_w, img_ln_b,
                                      wm_ln_w, wm_ln_b, stats, xnT);
  dim3 gpw(8, 12, 32);
  k_pw_gemm<<<gpw, 256, 0, stream>>>(Wpw, xnT, img_pw_b, wm_pw_b, Y);
  k_dw<<<24576, 256, 0, stream>>>(Y, img_dw_w, img_dw_b, wm_dw_w, wm_dw_b, QKV);
  k_attn_scores<<<128, 256, 0, stream>>>(QKV, ATg);
  k_attn_out<<<512, 256, 0, stream>>>(QKV, ATg, attnT);
  dim3 gpj(8, 4, 16);
  k_proj_gemm<<<gpj, 256, 0, stream>>>(projT, attnT, (float*)d_out);
}

// Round 2
// 400.129 us; speedup vs baseline: 1.1511x; 1.1511x over previous
//
#include <hip/hip_runtime.h>
#include <hip/hip_bf16.h>
#include <stdint.h>

// Problem dims: B=16, C=512, H=W=32, NH=8, HC=64, HW=1024, 3C=1536
#define Bn  16
#define Cch 512
#define C3  1536
#define HWp 1024

typedef __attribute__((ext_vector_type(8))) short bf16x8;   // 8 bf16 = 4 VGPRs (MFMA A/B frag)
typedef __attribute__((ext_vector_type(4))) float f32x4;    // MFMA C/D frag

#define DEV static __device__ __forceinline__

DEV float bflo(unsigned u) { return __builtin_bit_cast(float, u << 16); }
DEV float bfhi(unsigned u) { return __builtin_bit_cast(float, u & 0xffff0000u); }
DEV unsigned short f2bf(float f) {
  __hip_bfloat16 h = __float2bfloat16(f);
  return __builtin_bit_cast(unsigned short, h);
}

// async global->LDS, 16B per lane. LDS dest must be wave-uniform base + lane*16.
DEV void async16(__hip_bfloat16* lds, const __hip_bfloat16* g) {
  __builtin_amdgcn_global_load_lds(
      (const __attribute__((address_space(1))) unsigned*)g,
      (__attribute__((address_space(3))) unsigned*)lds, 16, 0, 0);
}

// ---------------- 1. weight prep: fp32 -> bf16 ----------------
__global__ __launch_bounds__(256) void k_prep(
    const float* __restrict__ img_pw_w, const float* __restrict__ wm_pw_w,
    const float* __restrict__ proj,
    __hip_bfloat16* __restrict__ Wpw, __hip_bfloat16* __restrict__ projT)
{
  int i = blockIdx.x * 256 + threadIdx.x;
  const int NW = C3 * Cch;  // 786432
  if (i < NW)          Wpw[i] = __float2bfloat16(img_pw_w[i]);
  else if (i < 2 * NW) Wpw[i] = __float2bfloat16(wm_pw_w[i - NW]);
  else {
    int j = i - 2 * NW;                 // 0..524287
    int c = j >> 10, d = j & 1023;
    projT[(size_t)c * 1024 + d] = __float2bfloat16(proj[(size_t)d * 512 + c]);
  }
}

// ---------------- 2. LayerNorm partial sums ----------------
__global__ __launch_bounds__(256) void k_ln_partial(
    const float* __restrict__ image, const float* __restrict__ watermark,
    float* __restrict__ part)
{
  int blk = blockIdx.x;
  int chunk = blk & 63, b = (blk >> 6) & 15, t = blk >> 10;
  const float* x = (t ? watermark : image) + (size_t)b * Cch * HWp + chunk * 8192;
  const float4* xv = (const float4*)x;
  float s = 0.f, ss = 0.f;
#pragma unroll
  for (int i = 0; i < 8; i++) {
    float4 v = xv[threadIdx.x + i * 256];
    s  += v.x + v.y + v.z + v.w;
    ss += v.x * v.x + v.y * v.y + v.z * v.z + v.w * v.w;
  }
#pragma unroll
  for (int off = 32; off; off >>= 1) { s += __shfl_down(s, off); ss += __shfl_down(ss, off); }
  __shared__ float ls[4], lss[4];
  int wv = threadIdx.x >> 6;
  if ((threadIdx.x & 63) == 0) { ls[wv] = s; lss[wv] = ss; }
  __syncthreads();
  if (threadIdx.x == 0) {
    part[blk * 2]     = ls[0] + ls[1] + ls[2] + ls[3];
    part[blk * 2 + 1] = lss[0] + lss[1] + lss[2] + lss[3];
  }
}

// ---------------- 3. finalize mu / rstd ----------------
__global__ void k_ln_final(const float* __restrict__ part, float* __restrict__ stats)
{
  int i = threadIdx.x;
  if (i < 32) {
    float S = 0.f, SS = 0.f;
    for (int c2 = 0; c2 < 64; c2++) { S += part[(i * 64 + c2) * 2]; SS += part[(i * 64 + c2) * 2 + 1]; }
    const float inv = 1.f / (float)(Cch * HWp);
    float mu  = S * inv;
    float var = SS * inv - mu * mu;
    stats[i]      = mu;
    stats[32 + i] = rsqrtf(var + 1e-5f);
  }
}

// ---------------- 4. normalize + affine + transpose -> xnT[t][b][p][c] bf16 ----------------
__global__ __launch_bounds__(256) void k_norm_t(
    const float* __restrict__ image, const float* __restrict__ watermark,
    const float* __restrict__ img_w, const float* __restrict__ img_b,
    const float* __restrict__ wm_w,  const float* __restrict__ wm_b,
    const float* __restrict__ stats, __hip_bfloat16* __restrict__ xnT)
{
  int blk = blockIdx.x;
  int ct = blk & 15, pt = (blk >> 4) & 31, b = (blk >> 9) & 15, t = blk >> 13;
  const float* x   = (t ? watermark : image) + (size_t)b * Cch * HWp;
  const float* wgt = t ? wm_w : img_w;
  const float* bia = t ? wm_b : img_b;
  float mu = stats[t * 16 + b], rstd = stats[32 + t * 16 + b];
  __shared__ float tile[32][33];
  int pl = threadIdx.x & 31, cl0 = threadIdx.x >> 5;
  int p = pt * 32 + pl;
#pragma unroll
  for (int k = 0; k < 4; k++) {
    int cl = cl0 + k * 8;
    int idx = (ct * 32 + cl) * HWp + p;
    tile[cl][pl] = (x[idx] - mu) * rstd * wgt[idx] + bia[idx];
  }
  __syncthreads();
  __hip_bfloat16* dst = xnT + ((size_t)(t * 16 + b)) * HWp * Cch;
#pragma unroll
  for (int k = 0; k < 4; k++) {
    int prow = cl0 + k * 8;
    dst[(size_t)(pt * 32 + prow) * Cch + ct * 32 + pl] = __float2bfloat16(tile[pl][prow]);
  }
}

// ---------------- 5. bf16 BT-GEMM core (m97 structure) ----------------
// C[m][n] = sum_k A[m][k]*Bt[n][k]. 128x128 tile, 4 waves (64x64 each, 4x4 MFMA),
// BK=64, global_load_lds width-16 staging into UNPADDED [128][64] LDS
// (async LDS dest must be wave-uniform base + lane*16: offset == tid*16 here).
template<int Kdim, int Ncols, bool OBF, bool HB>
DEV void gemm_core(const __hip_bfloat16* __restrict__ A,
                   const __hip_bfloat16* __restrict__ Bt,
                   const float* __restrict__ bias, void* __restrict__ Cout)
{
  __shared__ __hip_bfloat16 As[128 * 64];
  __shared__ __hip_bfloat16 Bs[128 * 64];
  const int tid = threadIdx.x, lane = tid & 63, wv = tid >> 6;
  const int lr = lane & 15, lq = lane >> 4;
  const int wm = (wv >> 1) * 64, wn = (wv & 1) * 64;
  const int m0 = blockIdx.y * 128, n0 = blockIdx.x * 128;
  f32x4 acc[4][4] = {};
  // staging map: LDS byte off = c*4096 + tid*16  ->  row = c*32 + tid/8, colseg = (tid&7)*8
  const int srow = tid >> 3, sseg = (tid & 7) * 8;
  for (int k0 = 0; k0 < Kdim; k0 += 64) {
#pragma unroll
    for (int c = 0; c < 4; c++) {
      int row = srow + c * 32;
      async16(&As[row * 64 + sseg], &A [(size_t)(m0 + row) * Kdim + k0 + sseg]);
      async16(&Bs[row * 64 + sseg], &Bt[(size_t)(n0 + row) * Kdim + k0 + sseg]);
    }
    __syncthreads();   // compiler emits vmcnt(0) drain here
#pragma unroll
    for (int ks = 0; ks < 2; ks++) {
      bf16x8 af[4], bfr[4];
#pragma unroll
      for (int mi = 0; mi < 4; mi++)
        af[mi]  = *(const bf16x8*)&As[(wm + mi * 16 + lr) * 64 + ks * 32 + lq * 8];
#pragma unroll
      for (int ni = 0; ni < 4; ni++)
        bfr[ni] = *(const bf16x8*)&Bs[(wn + ni * 16 + lr) * 64 + ks * 32 + lq * 8];
#pragma unroll
      for (int mi = 0; mi < 4; mi++)
#pragma unroll
        for (int ni = 0; ni < 4; ni++)
          acc[mi][ni] = __builtin_amdgcn_mfma_f32_16x16x32_bf16(af[mi], bfr[ni], acc[mi][ni], 0, 0, 0);
    }
    __syncthreads();
  }
#pragma unroll
  for (int mi = 0; mi < 4; mi++) {
    int mrow = m0 + wm + mi * 16 + lq * 4;
#pragma unroll
    for (int ni = 0; ni < 4; ni++) {
      int ncol = n0 + wn + ni * 16 + lr;
#pragma unroll
      for (int r = 0; r < 4; r++) {
        float y = acc[mi][ni][r];
        int row = mrow + r;
        if (HB) y += bias[row];
        if (OBF) ((__hip_bfloat16*)Cout)[(size_t)row * Ncols + ncol] = __float2bfloat16(y);
        else     ((float*)Cout)[(size_t)row * Ncols + ncol] = y;
      }
    }
  }
}

__global__ __launch_bounds__(256) void k_pw_gemm(
    const __hip_bfloat16* __restrict__ Wpw, const __hip_bfloat16* __restrict__ xnT,
    const float* __restrict__ img_pw_b, const float* __restrict__ wm_pw_b,
    __hip_bfloat16* __restrict__ Y)
{
  int bz = blockIdx.z, t = bz >> 4;
  gemm_core<512, 1024, true, true>(
      Wpw + (size_t)t * C3 * Cch,
      xnT + (size_t)bz * HWp * Cch,
      t ? wm_pw_b : img_pw_b,
      Y + (size_t)bz * C3 * HWp);
}

__global__ __launch_bounds__(256) void k_proj_gemm(
    const __hip_bfloat16* __restrict__ projT, const __hip_bfloat16* __restrict__ attnT,
    float* __restrict__ out)
{
  int b = blockIdx.z;
  gemm_core<1024, 1024, false, false>(
      projT, attnT + (size_t)b * HWp * 1024, nullptr, out + (size_t)b * Cch * HWp);
}

// ---------------- 6. depthwise 3x3 grouped conv ----------------
// thread = (tb, g, h, w-strip of 8), computes ALL 3 outputs of group g:
// unpack/mask cost amortized 3x; weights via readfirstlane -> scalar loads.
__global__ __launch_bounds__(256) void k_dw(
    const __hip_bfloat16* __restrict__ Y,
    const float* __restrict__ img_dw_w, const float* __restrict__ img_dw_b,
    const float* __restrict__ wm_dw_w,  const float* __restrict__ wm_dw_b,
    __hip_bfloat16* __restrict__ QKV)
{
  int idx = blockIdx.x * 256 + threadIdx.x;
  int w0 = (idx & 3) * 8;
  int h  = (idx >> 2) & 31;
  // g, tb are wave-uniform (idx bits >= 7); readfirstlane makes it provable -> s_loads
  int g  = __builtin_amdgcn_readfirstlane((idx >> 7) & 511);
  int tb = __builtin_amdgcn_readfirstlane(idx >> 16);
  int t  = tb >> 4;
  const float* dww = (t ? wm_dw_w : img_dw_w) + g * 81;   // 3 o x 27
  const float* dwb = (t ? wm_dw_b : img_dw_b) + g * 3;
  const __hip_bfloat16* base = Y + ((size_t)tb * C3 + g * 3) * HWp;
  float acc[3][8];
#pragma unroll
  for (int o = 0; o < 3; o++) {
    float bv = dwb[o];
#pragma unroll
    for (int w = 0; w < 8; w++) acc[o][w] = bv;
  }
  const bool mlo = (w0 == 0), mhi = (w0 == 24);
#pragma unroll
  for (int i = 0; i < 3; i++) {
#pragma unroll
    for (int kh = 0; kh < 3; kh++) {
      int hh = h + kh - 1;
      if ((unsigned)hh > 31u) continue;
      // 12 halfs covering w0-2 .. w0+9 (dword aligned; only v0,v1,v10,v11 can be OOB)
      const unsigned* up = (const unsigned*)(base + i * HWp + hh * 32 + (w0 - 2));
      float v[12];
#pragma unroll
      for (int d2 = 0; d2 < 6; d2++) { unsigned u = up[d2]; v[d2*2] = bflo(u); v[d2*2+1] = bfhi(u); }
      if (mlo) { v[0] = 0.f; v[1] = 0.f; }
      if (mhi) { v[10] = 0.f; v[11] = 0.f; }
#pragma unroll
      for (int o = 0; o < 3; o++) {
        float wk0 = dww[o*27 + i*9 + kh*3 + 0];
        float wk1 = dww[o*27 + i*9 + kh*3 + 1];
        float wk2 = dww[o*27 + i*9 + kh*3 + 2];
#pragma unroll
        for (int w = 0; w < 8; w++)
          acc[o][w] += v[w + 1] * wk0 + v[w + 2] * wk1 + v[w + 3] * wk2;
      }
    }
  }
#pragma unroll
  for (int o = 0; o < 3; o++) {
    union { unsigned short us[8]; uint4 v4; } pk;
#pragma unroll
    for (int w = 0; w < 8; w++) pk.us[w] = f2bf(acc[o][w]);
    *(uint4*)(QKV + ((size_t)tb * C3 + g * 3 + o) * HWp + h * 32 + w0) = pk.v4;
  }
}

// ---------------- 7. attention scores + softmax over q ----------------
__global__ __launch_bounds__(256) void k_attn_scores(
    const __hip_bfloat16* __restrict__ QKV, __hip_bfloat16* __restrict__ ATg)
{
  int bn = blockIdx.x, b = bn >> 3, nh = bn & 7;
  int tid = threadIdx.x, lane = tid & 63, wv = tid >> 6;
  int lr = lane & 15, lq = lane >> 4;
  const __hip_bfloat16* kbase[2];
#pragma unroll
  for (int kt = 0; kt < 2; kt++) {
    int krow = wv * 32 + kt * 16 + lr;          // 0..127 ; <64 -> Ki, >=64 -> Kw
    int tk = krow >> 6, hc = krow & 63;
    kbase[kt] = QKV + (((size_t)(tk * 16 + b)) * C3 + 512 + nh * 64 + hc) * HWp + lq * 8;
  }
  const __hip_bfloat16* qbase[2][4];
#pragma unroll
  for (int m = 0; m < 2; m++)
#pragma unroll
    for (int qt = 0; qt < 4; qt++)
      qbase[m][qt] = QKV + (((size_t)(m * 16 + b)) * C3 + nh * 64 + qt * 16 + lr) * HWp + lq * 8;

  f32x4 acc[2][2][4] = {};
  for (int p0 = 0; p0 < HWp; p0 += 32) {
    bf16x8 af[2];
#pragma unroll
    for (int kt = 0; kt < 2; kt++) af[kt] = *(const bf16x8*)(kbase[kt] + p0);
#pragma unroll
    for (int m = 0; m < 2; m++)
#pragma unroll
      for (int qt = 0; qt < 4; qt++) {
        bf16x8 bq = *(const bf16x8*)(qbase[m][qt] + p0);
#pragma unroll
        for (int kt = 0; kt < 2; kt++)
          acc[m][kt][qt] = __builtin_amdgcn_mfma_f32_16x16x32_bf16(af[kt], bq, acc[m][kt][qt], 0, 0, 0);
      }
  }
  __shared__ float SbufT[2][64][128];
#pragma unroll
  for (int m = 0; m < 2; m++)
#pragma unroll
    for (int kt = 0; kt < 2; kt++)
#pragma unroll
      for (int qt = 0; qt < 4; qt++)
#pragma unroll
        for (int r = 0; r < 4; r++)
          SbufT[m][qt * 16 + lr][wv * 32 + kt * 16 + lq * 4 + r] = acc[m][kt][qt][r];
  __syncthreads();
  int m = tid >> 7, k = tid & 127;   // 256 threads = 2m x 128k
  float vals[64], mx = -1e30f;
#pragma unroll
  for (int q = 0; q < 64; q++) { vals[q] = SbufT[m][q][k]; mx = fmaxf(mx, vals[q]); }
  float ssum = 0.f;
#pragma unroll
  for (int q = 0; q < 64; q++) { vals[q] = __expf(vals[q] - mx); ssum += vals[q]; }
  float inv = 1.f / ssum;
  __hip_bfloat16* outp = ATg + ((size_t)(bn * 2 + m)) * 64 * 128 + k;
#pragma unroll
  for (int q = 0; q < 64; q++) outp[(size_t)q * 128] = __float2bfloat16(vals[q] * inv);
}

// ---------------- 8. attention output ----------------
__global__ __launch_bounds__(256) void k_attn_out(
    const __hip_bfloat16* __restrict__ QKV, const __hip_bfloat16* __restrict__ ATg,
    __hip_bfloat16* __restrict__ attnT)
{
  int blk = blockIdx.x, pc = blk & 3, bn = blk >> 2, b = bn >> 3, nh = bn & 7;
  int tid = threadIdx.x, lane = tid & 63, wv = tid >> 6;
  int lr = lane & 15, lq = lane >> 4;
  __shared__ __hip_bfloat16 ATs[64][136];
  __shared__ __hip_bfloat16 VTs[64][136];
  for (int m = 0; m < 2; m++) {
    __syncthreads();
    {
      const __hip_bfloat16* src = ATg + ((size_t)(bn * 2 + m)) * 64 * 128;
#pragma unroll
      for (int s = 0; s < 4; s++) {
        int id = tid + s * 256, row = id >> 4, seg = (id & 15) * 8;
        *(uint4*)&ATs[row][seg] = *(const uint4*)&src[row * 128 + seg];
      }
    }
    for (int ps = 0; ps < 4; ps++) {
      int p0 = pc * 256 + ps * 64;
      __syncthreads();
#pragma unroll
      for (int s = 0; s < 4; s++) {
        int id = tid + s * 256;
        int k = id >> 3, seg = (id & 7) * 8;
        int tk = k >> 6, hc = k & 63;
        const __hip_bfloat16* vp =
            QKV + (((size_t)(tk * 16 + b)) * C3 + 1024 + nh * 64 + hc) * HWp + p0 + seg;
        uint4 pkv = *(const uint4*)vp;
        unsigned short* pv = (unsigned short*)&pkv;
#pragma unroll
        for (int e = 0; e < 8; e++) *(unsigned short*)&VTs[seg + e][k] = pv[e];
      }
      __syncthreads();
      f32x4 oacc[4] = {};
#pragma unroll
      for (int ks = 0; ks < 4; ks++) {
        bf16x8 bv = *(const bf16x8*)&VTs[wv * 16 + lr][ks * 32 + lq * 8];
#pragma unroll
        for (int qt = 0; qt < 4; qt++) {
          bf16x8 av = *(const bf16x8*)&ATs[qt * 16 + lr][ks * 32 + lq * 8];
          oacc[qt] = __builtin_amdgcn_mfma_f32_16x16x32_bf16(av, bv, oacc[qt], 0, 0, 0);
        }
      }
#pragma unroll
      for (int qt = 0; qt < 4; qt++) {
        int q = qt * 16 + lq * 4;
        int d = nh * 128 + m * 64 + q;
        int p = p0 + wv * 16 + lr;
        union { unsigned short us[4]; uint2 v2; } pk;
#pragma unroll
        for (int r = 0; r < 4; r++) pk.us[r] = f2bf(oacc[qt][r]);
        *(uint2*)&attnT[((size_t)b * HWp + p) * 1024 + d] = pk.v2;
      }
    }
  }
}

extern "C" void kernel_launch(void* const* d_in, const int* in_sizes, int n_in,
                              void* d_out, int out_size, void* d_ws, size_t ws_size,
                              hipStream_t stream)
{
  (void)in_sizes; (void)n_in; (void)out_size; (void)ws_size;
  const float* image     = (const float*)d_in[0];
  const float* watermark = (const float*)d_in[1];
  const float* img_ln_w  = (const float*)d_in[2];
  const float* img_ln_b  = (const float*)d_in[3];
  const float* wm_ln_w   = (const float*)d_in[4];
  const float* wm_ln_b   = (const float*)d_in[5];
  const float* img_pw_w  = (const float*)d_in[6];
  const float* img_pw_b  = (const float*)d_in[7];
  const float* img_dw_w  = (const float*)d_in[8];
  const float* img_dw_b  = (const float*)d_in[9];
  const float* wm_pw_w   = (const float*)d_in[10];
  const float* wm_pw_b   = (const float*)d_in[11];
  const float* wm_dw_w   = (const float*)d_in[12];
  const float* wm_dw_b   = (const float*)d_in[13];
  const float* proj      = (const float*)d_in[14];

  char* ws = (char*)d_ws;
  // workspace map (high-water ~232 MiB); aliases are lifetime-disjoint:
  //   attnT aliases xnT (xnT dead after k_pw_gemm); ATg aliases Y (Y dead after k_dw)
  __hip_bfloat16* Wpw    = (__hip_bfloat16*)(ws + 0);            // 3.0 MiB
  __hip_bfloat16* projT  = (__hip_bfloat16*)(ws + 3145728);      // 1.0 MiB
  float*          lnpart = (float*)(ws + 4194304);               // 16 KiB
  float*          stats  = (float*)(ws + 4210688);               // 256 B
  __hip_bfloat16* xnT    = (__hip_bfloat16*)(ws + 5242880);      // 32 MiB
  __hip_bfloat16* attnT  = xnT;                                  // alias
  __hip_bfloat16* Y      = (__hip_bfloat16*)(ws + 41943040);     // 96 MiB
  __hip_bfloat16* ATg    = Y;                                    // alias (4 MiB)
  __hip_bfloat16* QKV    = (__hip_bfloat16*)(ws + 142606336);    // 96 MiB

  k_prep<<<8192, 256, 0, stream>>>(img_pw_w, wm_pw_w, proj, Wpw, projT);
  k_ln_partial<<<2048, 256, 0, stream>>>(image, watermark, lnpart);
  k_ln_final<<<1, 64, 0, stream>>>(lnpart, stats);
  k_norm_t<<<16384, 256, 0, stream>>>(image, watermark, img_ln_w, img_ln_b,
                                      wm_ln_w, wm_ln_b, stats, xnT);
  dim3 gpw(8, 12, 32);
  k_pw_gemm<<<gpw, 256, 0, stream>>>(Wpw, xnT, img_pw_b, wm_pw_b, Y);
  k_dw<<<8192, 256, 0, stream>>>(Y, img_dw_w, img_dw_b, wm_dw_w, wm_dw_b, QKV);
  k_attn_scores<<<128, 256, 0, stream>>>(QKV, ATg);
  k_attn_out<<<512, 256, 0, stream>>>(QKV, ATg, attnT);
  dim3 gpj(8, 4, 16);
  k_proj_gemm<<<gpj, 256, 0, stream>>>(projT, attnT, (float*)d_out);
}

// Round 3
// 392.527 us; speedup vs baseline: 1.1734x; 1.0194x over previous
//
#include <hip/hip_runtime.h>
#include <hip/hip_bf16.h>
#include <stdint.h>

// Problem dims: B=16, C=512, H=W=32, NH=8, HC=64, HW=1024, 3C=1536
#define Bn  16
#define Cch 512
#define C3  1536
#define HWp 1024

typedef __attribute__((ext_vector_type(8))) short bf16x8;   // 8 bf16 = 4 VGPRs (MFMA A/B frag)
typedef __attribute__((ext_vector_type(4))) float f32x4;    // MFMA C/D frag

#define DEV static __device__ __forceinline__

DEV float bflo(unsigned u) { return __builtin_bit_cast(float, u << 16); }
DEV float bfhi(unsigned u) { return __builtin_bit_cast(float, u & 0xffff0000u); }
DEV unsigned short f2bf(float f) {
  __hip_bfloat16 h = __float2bfloat16(f);
  return __builtin_bit_cast(unsigned short, h);
}

// async global->LDS, 16B per lane. LDS dest must be wave-uniform base + lane*16.
DEV void async16(__hip_bfloat16* lds, const __hip_bfloat16* g) {
  __builtin_amdgcn_global_load_lds(
      (const __attribute__((address_space(1))) unsigned*)g,
      (__attribute__((address_space(3))) unsigned*)lds, 16, 0, 0);
}

// ---------------- 1. weight prep: fp32 -> bf16 ----------------
__global__ __launch_bounds__(256) void k_prep(
    const float* __restrict__ img_pw_w, const float* __restrict__ wm_pw_w,
    const float* __restrict__ proj,
    __hip_bfloat16* __restrict__ Wpw, __hip_bfloat16* __restrict__ projT)
{
  int i = blockIdx.x * 256 + threadIdx.x;
  const int NW = C3 * Cch;  // 786432
  if (i < NW)          Wpw[i] = __float2bfloat16(img_pw_w[i]);
  else if (i < 2 * NW) Wpw[i] = __float2bfloat16(wm_pw_w[i - NW]);
  else {
    int j = i - 2 * NW;                 // 0..524287
    int c = j >> 10, d = j & 1023;
    projT[(size_t)c * 1024 + d] = __float2bfloat16(proj[(size_t)d * 512 + c]);
  }
}

// ---------------- 2. LayerNorm partial sums ----------------
__global__ __launch_bounds__(256) void k_ln_partial(
    const float* __restrict__ image, const float* __restrict__ watermark,
    float* __restrict__ part)
{
  int blk = blockIdx.x;
  int chunk = blk & 63, b = (blk >> 6) & 15, t = blk >> 10;
  const float* x = (t ? watermark : image) + (size_t)b * Cch * HWp + chunk * 8192;
  const float4* xv = (const float4*)x;
  float s = 0.f, ss = 0.f;
#pragma unroll
  for (int i = 0; i < 8; i++) {
    float4 v = xv[threadIdx.x + i * 256];
    s  += v.x + v.y + v.z + v.w;
    ss += v.x * v.x + v.y * v.y + v.z * v.z + v.w * v.w;
  }
#pragma unroll
  for (int off = 32; off; off >>= 1) { s += __shfl_down(s, off); ss += __shfl_down(ss, off); }
  __shared__ float ls[4], lss[4];
  int wv = threadIdx.x >> 6;
  if ((threadIdx.x & 63) == 0) { ls[wv] = s; lss[wv] = ss; }
  __syncthreads();
  if (threadIdx.x == 0) {
    part[blk * 2]     = ls[0] + ls[1] + ls[2] + ls[3];
    part[blk * 2 + 1] = lss[0] + lss[1] + lss[2] + lss[3];
  }
}

// ---------------- 3. finalize mu / rstd ----------------
__global__ void k_ln_final(const float* __restrict__ part, float* __restrict__ stats)
{
  int i = threadIdx.x;
  if (i < 32) {
    float S = 0.f, SS = 0.f;
    for (int c2 = 0; c2 < 64; c2++) { S += part[(i * 64 + c2) * 2]; SS += part[(i * 64 + c2) * 2 + 1]; }
    const float inv = 1.f / (float)(Cch * HWp);
    float mu  = S * inv;
    float var = SS * inv - mu * mu;
    stats[i]      = mu;
    stats[32 + i] = rsqrtf(var + 1e-5f);
  }
}

// ---------------- 4. normalize + affine + transpose -> xnT[t][b][p][c] bf16 ----------------
// v2: float4 global loads (x,w,b), fp32 LDS tile (c-stride 66 dwords: float2-aligned,
// 2-way-max bank aliasing both phases), uint4 (8xbf16) coalesced stores.
// grid 8192 = t*4096 + b*256 + pt*16 + ct; tile = 32 c x 64 p.
__global__ __launch_bounds__(256) void k_norm_t(
    const float* __restrict__ image, const float* __restrict__ watermark,
    const float* __restrict__ img_w, const float* __restrict__ img_b,
    const float* __restrict__ wm_w,  const float* __restrict__ wm_b,
    const float* __restrict__ stats, __hip_bfloat16* __restrict__ xnT)
{
  int blk = blockIdx.x;
  int ct = blk & 15, pt = (blk >> 4) & 15, b = (blk >> 8) & 15, t = blk >> 12;
  int c0 = ct * 32, p0 = pt * 64;
  const float* x   = (t ? watermark : image) + (size_t)b * Cch * HWp;
  const float* wgt = t ? wm_w : img_w;
  const float* bia = t ? wm_b : img_b;
  float mu = stats[t * 16 + b], rstd = stats[32 + t * 16 + b];
  __shared__ float tile[32 * 66];
  int tid = threadIdx.x;
  {
    int c = tid >> 3, s = tid & 7;
    const float* xr = x   + (size_t)(c0 + c) * HWp + p0;
    const float* wr = wgt + (size_t)(c0 + c) * HWp + p0;
    const float* br = bia + (size_t)(c0 + c) * HWp + p0;
#pragma unroll
    for (int j = 0; j < 2; j++) {
      int f = s + j * 8;                 // float4 slot 0..15
      float4 xv = *(const float4*)&xr[f * 4];
      float4 wv = *(const float4*)&wr[f * 4];
      float4 bv = *(const float4*)&br[f * 4];
      float n0 = (xv.x - mu) * rstd * wv.x + bv.x;
      float n1 = (xv.y - mu) * rstd * wv.y + bv.y;
      float n2 = (xv.z - mu) * rstd * wv.z + bv.z;
      float n3 = (xv.w - mu) * rstd * wv.w + bv.w;
      *(float2*)&tile[c * 66 + f * 4]     = make_float2(n0, n1);
      *(float2*)&tile[c * 66 + f * 4 + 2] = make_float2(n2, n3);
    }
  }
  __syncthreads();
  {
    int p = tid >> 2, cq = tid & 3;      // 64 p x 4 c-groups of 8
    union { unsigned short us[8]; uint4 v4; } pk;
#pragma unroll
    for (int j = 0; j < 8; j++) pk.us[j] = f2bf(tile[(cq * 8 + j) * 66 + p]);
    __hip_bfloat16* dst = xnT + ((size_t)(t * 16 + b)) * HWp * Cch
                        + (size_t)(p0 + p) * Cch + c0 + cq * 8;
    *(uint4*)dst = pk.v4;
  }
}

// ---------------- 5. bf16 BT-GEMM core (m97 structure) ----------------
// C[m][n] = sum_k A[m][k]*Bt[n][k]. MT(=MI*32) x 128 tile, 4 waves, BK=64,
// global_load_lds width-16 staging into UNPADDED [MT|128][64] LDS.
template<int MI, int Kdim, int Ncols, bool OBF, bool HB>
DEV void gemm_core(const __hip_bfloat16* __restrict__ A,
                   const __hip_bfloat16* __restrict__ Bt,
                   const float* __restrict__ bias, void* __restrict__ Cout)
{
  constexpr int MT = MI * 32;
  __shared__ __hip_bfloat16 As[MT * 64];
  __shared__ __hip_bfloat16 Bs[128 * 64];
  const int tid = threadIdx.x, lane = tid & 63, wv = tid >> 6;
  const int lr = lane & 15, lq = lane >> 4;
  const int wm = (wv >> 1) * (MI * 16), wn = (wv & 1) * 64;
  const int m0 = blockIdx.y * MT, n0 = blockIdx.x * 128;
  f32x4 acc[MI][4] = {};
  // staging map: LDS byte off = c*4096 + tid*16  ->  row = c*32 + tid/8, colseg = (tid&7)*8
  const int srow = tid >> 3, sseg = (tid & 7) * 8;
  for (int k0 = 0; k0 < Kdim; k0 += 64) {
#pragma unroll
    for (int c = 0; c < MI; c++) {
      int row = srow + c * 32;
      async16(&As[row * 64 + sseg], &A[(size_t)(m0 + row) * Kdim + k0 + sseg]);
    }
#pragma unroll
    for (int c = 0; c < 4; c++) {
      int row = srow + c * 32;
      async16(&Bs[row * 64 + sseg], &Bt[(size_t)(n0 + row) * Kdim + k0 + sseg]);
    }
    __syncthreads();   // compiler emits vmcnt(0) drain here
#pragma unroll
    for (int ks = 0; ks < 2; ks++) {
      bf16x8 af[MI], bfr[4];
#pragma unroll
      for (int mi = 0; mi < MI; mi++)
        af[mi]  = *(const bf16x8*)&As[(wm + mi * 16 + lr) * 64 + ks * 32 + lq * 8];
#pragma unroll
      for (int ni = 0; ni < 4; ni++)
        bfr[ni] = *(const bf16x8*)&Bs[(wn + ni * 16 + lr) * 64 + ks * 32 + lq * 8];
#pragma unroll
      for (int mi = 0; mi < MI; mi++)
#pragma unroll
        for (int ni = 0; ni < 4; ni++)
          acc[mi][ni] = __builtin_amdgcn_mfma_f32_16x16x32_bf16(af[mi], bfr[ni], acc[mi][ni], 0, 0, 0);
    }
    __syncthreads();
  }
#pragma unroll
  for (int mi = 0; mi < MI; mi++) {
    int mrow = m0 + wm + mi * 16 + lq * 4;
#pragma unroll
    for (int ni = 0; ni < 4; ni++) {
      int ncol = n0 + wn + ni * 16 + lr;
#pragma unroll
      for (int r = 0; r < 4; r++) {
        float y = acc[mi][ni][r];
        int row = mrow + r;
        if (HB) y += bias[row];
        if (OBF) ((__hip_bfloat16*)Cout)[(size_t)row * Ncols + ncol] = __float2bfloat16(y);
        else     ((float*)Cout)[(size_t)row * Ncols + ncol] = y;
      }
    }
  }
}

__global__ __launch_bounds__(256) void k_pw_gemm(
    const __hip_bfloat16* __restrict__ Wpw, const __hip_bfloat16* __restrict__ xnT,
    const float* __restrict__ img_pw_b, const float* __restrict__ wm_pw_b,
    __hip_bfloat16* __restrict__ Y)
{
  int bz = blockIdx.z, t = bz >> 4;
  gemm_core<4, 512, 1024, true, true>(
      Wpw + (size_t)t * C3 * Cch,
      xnT + (size_t)bz * HWp * Cch,
      t ? wm_pw_b : img_pw_b,
      Y + (size_t)bz * C3 * HWp);
}

// 64x128 tiles -> 1024 blocks (4/CU) so the K-loop barrier drains have TLP cover.
__global__ __launch_bounds__(256) void k_proj_gemm(
    const __hip_bfloat16* __restrict__ projT, const __hip_bfloat16* __restrict__ attnT,
    float* __restrict__ out)
{
  int b = blockIdx.z;
  gemm_core<2, 1024, 1024, false, false>(
      projT, attnT + (size_t)b * HWp * 1024, nullptr, out + (size_t)b * Cch * HWp);
}

// ---------------- 6. depthwise 3x3 grouped conv ----------------
__global__ __launch_bounds__(256) void k_dw(
    const __hip_bfloat16* __restrict__ Y,
    const float* __restrict__ img_dw_w, const float* __restrict__ img_dw_b,
    const float* __restrict__ wm_dw_w,  const float* __restrict__ wm_dw_b,
    __hip_bfloat16* __restrict__ QKV)
{
  int idx = blockIdx.x * 256 + threadIdx.x;
  int w0 = (idx & 3) * 8;
  int h  = (idx >> 2) & 31;
  int g  = __builtin_amdgcn_readfirstlane((idx >> 7) & 511);
  int tb = __builtin_amdgcn_readfirstlane(idx >> 16);
  int t  = tb >> 4;
  const float* dww = (t ? wm_dw_w : img_dw_w) + g * 81;   // 3 o x 27
  const float* dwb = (t ? wm_dw_b : img_dw_b) + g * 3;
  const __hip_bfloat16* base = Y + ((size_t)tb * C3 + g * 3) * HWp;
  float acc[3][8];
#pragma unroll
  for (int o = 0; o < 3; o++) {
    float bv = dwb[o];
#pragma unroll
    for (int w = 0; w < 8; w++) acc[o][w] = bv;
  }
  const bool mlo = (w0 == 0), mhi = (w0 == 24);
#pragma unroll
  for (int i = 0; i < 3; i++) {
#pragma unroll
    for (int kh = 0; kh < 3; kh++) {
      int hh = h + kh - 1;
      if ((unsigned)hh > 31u) continue;
      const unsigned* up = (const unsigned*)(base + i * HWp + hh * 32 + (w0 - 2));
      float v[12];
#pragma unroll
      for (int d2 = 0; d2 < 6; d2++) { unsigned u = up[d2]; v[d2*2] = bflo(u); v[d2*2+1] = bfhi(u); }
      if (mlo) { v[0] = 0.f; v[1] = 0.f; }
      if (mhi) { v[10] = 0.f; v[11] = 0.f; }
#pragma unroll
      for (int o = 0; o < 3; o++) {
        float wk0 = dww[o*27 + i*9 + kh*3 + 0];
        float wk1 = dww[o*27 + i*9 + kh*3 + 1];
        float wk2 = dww[o*27 + i*9 + kh*3 + 2];
#pragma unroll
        for (int w = 0; w < 8; w++)
          acc[o][w] += v[w + 1] * wk0 + v[w + 2] * wk1 + v[w + 3] * wk2;
      }
    }
  }
#pragma unroll
  for (int o = 0; o < 3; o++) {
    union { unsigned short us[8]; uint4 v4; } pk;
#pragma unroll
    for (int w = 0; w < 8; w++) pk.us[w] = f2bf(acc[o][w]);
    *(uint4*)(QKV + ((size_t)tb * C3 + g * 3 + o) * HWp + h * 32 + w0) = pk.v4;
  }
}

// ---------------- 7. attention scores + softmax over q ----------------
// v2: m-split -> grid 256 (full CU coverage, half the latency chain per block).
__global__ __launch_bounds__(256) void k_attn_scores(
    const __hip_bfloat16* __restrict__ QKV, __hip_bfloat16* __restrict__ ATg)
{
  int blk = blockIdx.x, m = blk & 1, bn = blk >> 1;
  int b = bn >> 3, nh = bn & 7;
  int tid = threadIdx.x, lane = tid & 63, wv = tid >> 6;
  int lr = lane & 15, lq = lane >> 4;
  const __hip_bfloat16* kbase[2];
#pragma unroll
  for (int kt = 0; kt < 2; kt++) {
    int krow = wv * 32 + kt * 16 + lr;          // 0..127 ; <64 -> Ki, >=64 -> Kw
    int tk = krow >> 6, hc = krow & 63;
    kbase[kt] = QKV + (((size_t)(tk * 16 + b)) * C3 + 512 + nh * 64 + hc) * HWp + lq * 8;
  }
  const __hip_bfloat16* qbase[4];
#pragma unroll
  for (int qt = 0; qt < 4; qt++)
    qbase[qt] = QKV + (((size_t)(m * 16 + b)) * C3 + nh * 64 + qt * 16 + lr) * HWp + lq * 8;

  f32x4 acc[2][4] = {};
  for (int p0 = 0; p0 < HWp; p0 += 32) {
    bf16x8 af[2];
#pragma unroll
    for (int kt = 0; kt < 2; kt++) af[kt] = *(const bf16x8*)(kbase[kt] + p0);
#pragma unroll
    for (int qt = 0; qt < 4; qt++) {
      bf16x8 bq = *(const bf16x8*)(qbase[qt] + p0);
#pragma unroll
      for (int kt = 0; kt < 2; kt++)
        acc[kt][qt] = __builtin_amdgcn_mfma_f32_16x16x32_bf16(af[kt], bq, acc[kt][qt], 0, 0, 0);
    }
  }
  // S^T in LDS: [q][k] (pad 129 -> 2-way max)
  __shared__ float S[64][129];
  __shared__ float red[2][2][128];
#pragma unroll
  for (int kt = 0; kt < 2; kt++)
#pragma unroll
    for (int qt = 0; qt < 4; qt++)
#pragma unroll
      for (int r = 0; r < 4; r++)
        S[qt * 16 + lr][wv * 32 + kt * 16 + lq * 4 + r] = acc[kt][qt][r];
  __syncthreads();
  int k = tid & 127, qh = tid >> 7;   // 256 threads = 128k x 2 q-halves
  float vals[32], mx = -1e30f;
#pragma unroll
  for (int j = 0; j < 32; j++) { vals[j] = S[qh * 32 + j][k]; mx = fmaxf(mx, vals[j]); }
  red[0][qh][k] = mx;
  __syncthreads();
  float M = fmaxf(red[0][0][k], red[0][1][k]);
  float ssum = 0.f;
#pragma unroll
  for (int j = 0; j < 32; j++) { vals[j] = __expf(vals[j] - M); ssum += vals[j]; }
  red[1][qh][k] = ssum;
  __syncthreads();
  float inv = 1.f / (red[1][0][k] + red[1][1][k]);
  __hip_bfloat16* outp = ATg + (((size_t)(bn * 2 + m)) * 64 + qh * 32) * 128 + k;
#pragma unroll
  for (int j = 0; j < 32; j++) outp[(size_t)j * 128] = __float2bfloat16(vals[j] * inv);
}

// ---------------- 8. attention output ----------------
__global__ __launch_bounds__(256) void k_attn_out(
    const __hip_bfloat16* __restrict__ QKV, const __hip_bfloat16* __restrict__ ATg,
    __hip_bfloat16* __restrict__ attnT)
{
  int blk = blockIdx.x, pc = blk & 3, bn = blk >> 2, b = bn >> 3, nh = bn & 7;
  int tid = threadIdx.x, lane = tid & 63, wv = tid >> 6;
  int lr = lane & 15, lq = lane >> 4;
  __shared__ __hip_bfloat16 ATs[64][136];
  __shared__ __hip_bfloat16 VTs[64][136];
  for (int m = 0; m < 2; m++) {
    __syncthreads();
    {
      const __hip_bfloat16* src = ATg + ((size_t)(bn * 2 + m)) * 64 * 128;
#pragma unroll
      for (int s = 0; s < 4; s++) {
        int id = tid + s * 256, row = id >> 4, seg = (id & 15) * 8;
        *(uint4*)&ATs[row][seg] = *(const uint4*)&src[row * 128 + seg];
      }
    }
    for (int ps = 0; ps < 4; ps++) {
      int p0 = pc * 256 + ps * 64;
      __syncthreads();
#pragma unroll
      for (int s = 0; s < 4; s++) {
        int id = tid + s * 256;
        int k = id >> 3, seg = (id & 7) * 8;
        int tk = k >> 6, hc = k & 63;
        const __hip_bfloat16* vp =
            QKV + (((size_t)(tk * 16 + b)) * C3 + 1024 + nh * 64 + hc) * HWp + p0 + seg;
        uint4 pkv = *(const uint4*)vp;
        unsigned short* pv = (unsigned short*)&pkv;
#pragma unroll
        for (int e = 0; e < 8; e++) *(unsigned short*)&VTs[seg + e][k] = pv[e];
      }
      __syncthreads();
      f32x4 oacc[4] = {};
#pragma unroll
      for (int ks = 0; ks < 4; ks++) {
        bf16x8 bv = *(const bf16x8*)&VTs[wv * 16 + lr][ks * 32 + lq * 8];
#pragma unroll
        for (int qt = 0; qt < 4; qt++) {
          bf16x8 av = *(const bf16x8*)&ATs[qt * 16 + lr][ks * 32 + lq * 8];
          oacc[qt] = __builtin_amdgcn_mfma_f32_16x16x32_bf16(av, bv, oacc[qt], 0, 0, 0);
        }
      }
#pragma unroll
      for (int qt = 0; qt < 4; qt++) {
        int q = qt * 16 + lq * 4;
        int d = nh * 128 + m * 64 + q;
        int p = p0 + wv * 16 + lr;
        union { unsigned short us[4]; uint2 v2; } pk;
#pragma unroll
        for (int r = 0; r < 4; r++) pk.us[r] = f2bf(oacc[qt][r]);
        *(uint2*)&attnT[((size_t)b * HWp + p) * 1024 + d] = pk.v2;
      }
    }
  }
}

extern "C" void kernel_launch(void* const* d_in, const int* in_sizes, int n_in,
                              void* d_out, int out_size, void* d_ws, size_t ws_size,
                              hipStream_t stream)
{
  (void)in_sizes; (void)n_in; (void)out_size; (void)ws_size;
  const float* image     = (const float*)d_in[0];
  const float* watermark = (const float*)d_in[1];
  const float* img_ln_w  = (const float*)d_in[2];
  const float* img_ln_b  = (const float*)d_in[3];
  const float* wm_ln_w   = (const float*)d_in[4];
  const float* wm_ln_b   = (const float*)d_in[5];
  const float* img_pw_w  = (const float*)d_in[6];
  const float* img_pw_b  = (const float*)d_in[7];
  const float* img_dw_w  = (const float*)d_in[8];
  const float* img_dw_b  = (const float*)d_in[9];
  const float* wm_pw_w   = (const float*)d_in[10];
  const float* wm_pw_b   = (const float*)d_in[11];
  const float* wm_dw_w   = (const float*)d_in[12];
  const float* wm_dw_b   = (const float*)d_in[13];
  const float* proj      = (const float*)d_in[14];

  char* ws = (char*)d_ws;
  // workspace map (high-water ~232 MiB); aliases are lifetime-disjoint:
  //   attnT aliases xnT (xnT dead after k_pw_gemm); ATg aliases Y (Y dead after k_dw)
  __hip_bfloat16* Wpw    = (__hip_bfloat16*)(ws + 0);            // 3.0 MiB
  __hip_bfloat16* projT  = (__hip_bfloat16*)(ws + 3145728);      // 1.0 MiB
  float*          lnpart = (float*)(ws + 4194304);               // 16 KiB
  float*          stats  = (float*)(ws + 4210688);               // 256 B
  __hip_bfloat16* xnT    = (__hip_bfloat16*)(ws + 5242880);      // 32 MiB
  __hip_bfloat16* attnT  = xnT;                                  // alias
  __hip_bfloat16* Y      = (__hip_bfloat16*)(ws + 41943040);     // 96 MiB
  __hip_bfloat16* ATg    = Y;                                    // alias (4 MiB)
  __hip_bfloat16* QKV    = (__hip_bfloat16*)(ws + 142606336);    // 96 MiB

  k_prep<<<8192, 256, 0, stream>>>(img_pw_w, wm_pw_w, proj, Wpw, projT);
  k_ln_partial<<<2048, 256, 0, stream>>>(image, watermark, lnpart);
  k_ln_final<<<1, 64, 0, stream>>>(lnpart, stats);
  k_norm_t<<<8192, 256, 0, stream>>>(image, watermark, img_ln_w, img_ln_b,
                                     wm_ln_w, wm_ln_b, stats, xnT);
  dim3 gpw(8, 12, 32);
  k_pw_gemm<<<gpw, 256, 0, stream>>>(Wpw, xnT, img_pw_b, wm_pw_b, Y);
  k_dw<<<8192, 256, 0, stream>>>(Y, img_dw_w, img_dw_b, wm_dw_w, wm_dw_b, QKV);
  k_attn_scores<<<256, 256, 0, stream>>>(QKV, ATg);
  k_attn_out<<<512, 256, 0, stream>>>(QKV, ATg, attnT);
  dim3 gpj(8, 8, 16);
  k_proj_gemm<<<gpj, 256, 0, stream>>>(projT, attnT, (float*)d_out);
}